// Round 2
// baseline (109.331 us; speedup 1.0000x reference)
//
#include <hip/hip_runtime.h>

// filtfilt with a=[1,0] (pure FIR, zero ICs both passes) collapses per row to:
//   y[n]   = (b0^2+b1^2)*x[n] + b0*b1*(x[n-1]+x[n+1])   for 0 <= n < T-1 (x[-1]=0)
//   y[T-1] =  b0^2     *x[T-1] + b0*b1* x[T-2]          (no y1[T] term)
// then clip to [-1,1].

#define T_LEN 1048576LL          // row length (2^20), from the reference
#define T4 (T_LEN / 4)           // float4s per row

__global__ __launch_bounds__(256) void preem_filtfilt_kernel(
    const float* __restrict__ x,
    const float* __restrict__ b,
    float* __restrict__ out,
    long long n4)
{
    const float b0 = b[0];
    const float b1 = b[1];
    const float c0 = b0 * b0 + b1 * b1;   // center tap (interior)
    const float c1 = b0 * b1;             // neighbor tap
    const float c0_last = b0 * b0;        // center tap at n = T-1

    const float4* __restrict__ x4 = (const float4*)x;
    float4* __restrict__ o4 = (float4*)out;

    const long long stride = (long long)gridDim.x * blockDim.x;
    for (long long i = (long long)blockIdx.x * blockDim.x + threadIdx.x;
         i < n4; i += stride) {
        const long long col4 = i & (T4 - 1);   // position within row (in float4s)
        const bool last4 = (col4 == T4 - 1);
        const float4 v = x4[i];
        const float prev = (col4 == 0) ? 0.0f : x[i * 4 - 1];
        const float next = last4       ? 0.0f : x[i * 4 + 4];
        const float cw   = last4 ? c0_last : c0;   // coefficient for .w element

        float4 o;
        o.x = c0 * v.x + c1 * (prev + v.y);
        o.y = c0 * v.y + c1 * (v.x + v.z);
        o.z = c0 * v.z + c1 * (v.y + v.w);
        o.w = cw * v.w + c1 * (v.z + next);

        o.x = fminf(fmaxf(o.x, -1.0f), 1.0f);
        o.y = fminf(fmaxf(o.y, -1.0f), 1.0f);
        o.z = fminf(fmaxf(o.z, -1.0f), 1.0f);
        o.w = fminf(fmaxf(o.w, -1.0f), 1.0f);

        o4[i] = o;
    }
}

extern "C" void kernel_launch(void* const* d_in, const int* in_sizes, int n_in,
                              void* d_out, int out_size, void* d_ws, size_t ws_size,
                              hipStream_t stream) {
    const float* x = (const float*)d_in[0];
    const float* b = (const float*)d_in[1];
    float* out = (float*)d_out;

    const long long n = (long long)in_sizes[0];   // B*T = 67,108,864
    const long long n4 = n / 4;                   // 16,777,216 float4s

    const int block = 256;
    long long want = (n4 + block - 1) / block;
    int grid = (int)((want < 4096) ? want : 4096);

    preem_filtfilt_kernel<<<grid, block, 0, stream>>>(x, b, out, n4);
}

// Round 4
// 99.866 us; speedup vs baseline: 1.0948x; 1.0948x over previous
//
#include <hip/hip_runtime.h>

// filtfilt with a=[1,0] (pure FIR, zero ICs both passes) collapses per row to:
//   y[n]   = (b0^2+b1^2)*x[n] + b0*b1*(x[n-1]+x[n+1])   for 0 <= n < T-1 (x[-1]=0)
//   y[T-1] =  b0^2     *x[T-1] + b0*b1* x[T-2]          (no y1[T] term)
// then clip to [-1,1].
//
// 32 B/thread (two 16B vectors); cross-lane neighbors via wave shuffles. T/8 is
// a multiple of 64, so row boundaries only ever land on lanes 0/63 of a wave.

typedef float fx4 __attribute__((ext_vector_type(4)));   // native clang vector

#define T_LEN 1048576LL          // row length (2^20), from the reference
#define T8 (T_LEN / 8)           // 32B-chunks per row (131072, multiple of 64)

__global__ __launch_bounds__(256) void preem_filtfilt_kernel(
    const float* __restrict__ x,
    const float* __restrict__ b,
    float* __restrict__ out,
    long long n8)
{
    const float b0 = b[0];
    const float b1 = b[1];
    const float c0 = b0 * b0 + b1 * b1;   // center tap (interior)
    const float c1 = b0 * b1;             // neighbor tap
    const float c0_last = b0 * b0;        // center tap at n = T-1

    const int lane = threadIdx.x & 63;
    const long long stride = (long long)gridDim.x * blockDim.x;

    for (long long i = (long long)blockIdx.x * blockDim.x + threadIdx.x;
         i < n8; i += stride) {
        const long long base = i * 8;
        const fx4 v0 = *(const fx4*)(x + base);
        const fx4 v1 = *(const fx4*)(x + base + 4);

        // cross-lane neighbors (lane i-1's v1.w, lane i+1's v0.x)
        float prev = __shfl_up(v1.w, 1, 64);
        float next = __shfl_down(v0.x, 1, 64);

        const long long col8 = i & (T8 - 1);
        const bool first = (col8 == 0);        // only possible at lane 0
        const bool last  = (col8 == T8 - 1);   // only possible at lane 63
        if (lane == 0)  prev = first ? 0.0f : x[base - 1];
        if (lane == 63) next = last  ? 0.0f : x[base + 8];
        const float cw = last ? c0_last : c0;

        fx4 o0, o1;
        o0.x = c0 * v0.x + c1 * (prev + v0.y);
        o0.y = c0 * v0.y + c1 * (v0.x + v0.z);
        o0.z = c0 * v0.z + c1 * (v0.y + v0.w);
        o0.w = c0 * v0.w + c1 * (v0.z + v1.x);
        o1.x = c0 * v1.x + c1 * (v0.w + v1.y);
        o1.y = c0 * v1.y + c1 * (v1.x + v1.z);
        o1.z = c0 * v1.z + c1 * (v1.y + v1.w);
        o1.w = cw * v1.w + c1 * (v1.z + next);

        o0.x = fminf(fmaxf(o0.x, -1.0f), 1.0f);
        o0.y = fminf(fmaxf(o0.y, -1.0f), 1.0f);
        o0.z = fminf(fmaxf(o0.z, -1.0f), 1.0f);
        o0.w = fminf(fmaxf(o0.w, -1.0f), 1.0f);
        o1.x = fminf(fmaxf(o1.x, -1.0f), 1.0f);
        o1.y = fminf(fmaxf(o1.y, -1.0f), 1.0f);
        o1.z = fminf(fmaxf(o1.z, -1.0f), 1.0f);
        o1.w = fminf(fmaxf(o1.w, -1.0f), 1.0f);

        __builtin_nontemporal_store(o0, (fx4*)(out + base));
        __builtin_nontemporal_store(o1, (fx4*)(out + base + 4));
    }
}

extern "C" void kernel_launch(void* const* d_in, const int* in_sizes, int n_in,
                              void* d_out, int out_size, void* d_ws, size_t ws_size,
                              hipStream_t stream) {
    const float* x = (const float*)d_in[0];
    const float* b = (const float*)d_in[1];
    float* out = (float*)d_out;

    const long long n = (long long)in_sizes[0];   // B*T = 67,108,864
    const long long n8 = n / 8;                   // 8,388,608 32B-chunks

    const int block = 256;
    long long want = (n8 + block - 1) / block;
    int grid = (int)((want < 4096) ? want : 4096);

    preem_filtfilt_kernel<<<grid, block, 0, stream>>>(x, b, out, n8);
}